// Round 11
// baseline (471.972 us; speedup 1.0000x reference)
//
#include <hip/hip_runtime.h>

// GraphSAGE 3-layer, N=100k E=640k D=128.
// edge_index arrives as int32 (harness converts integer inputs to int32).
// CSR build: XCD-partitioned count -> hierarchical scan -> XCD-partitioned fill.
// Per layer: mean-aggregate (16 lanes/node, unroll-2 gather pipeline),
//   LDS-free fused GEMM: out = agg@Wl^T + x@Wr^T + b via mfma_f32_16x16x32_bf16,
//   B-fragments read from pre-converted bf16 W (L1/L2-resident, 64KB/layer).

typedef __attribute__((ext_vector_type(8))) short bf16x8;
typedef __attribute__((ext_vector_type(4))) float f32x4;
typedef __attribute__((ext_vector_type(4))) unsigned int u32x4;

__device__ __forceinline__ unsigned short f2bf(float f) {
  unsigned u = __float_as_uint(f);
  u += 0x7fffu + ((u >> 16) & 1u);   // RNE
  return (unsigned short)(u >> 16);
}

// ---------- fp32 -> bf16 convert, 8 elems/thread ----------
__global__ __launch_bounds__(256) void cvt_kernel(const float* __restrict__ in,
                                                  unsigned short* __restrict__ out, int n8) {
  int i = blockIdx.x * 256 + threadIdx.x;
  if (i >= n8) return;
  const float4* p = (const float4*)(in + (size_t)i * 8);
  float4 a = p[0], b = p[1];
  union { unsigned short s[8]; u32x4 u; } pk;
  pk.s[0] = f2bf(a.x); pk.s[1] = f2bf(a.y); pk.s[2] = f2bf(a.z); pk.s[3] = f2bf(a.w);
  pk.s[4] = f2bf(b.x); pk.s[5] = f2bf(b.y); pk.s[6] = f2bf(b.z); pk.s[7] = f2bf(b.w);
  *(u32x4*)(out + (size_t)i * 8) = pk.u;
}

// ---------- convert 6 weight matrices (128x128 each) to bf16, one launch ----------
__global__ __launch_bounds__(256) void wcvt_kernel(const float* __restrict__ w0, const float* __restrict__ w1,
                                                   const float* __restrict__ w2, const float* __restrict__ w3,
                                                   const float* __restrict__ w4, const float* __restrict__ w5,
                                                   unsigned short* __restrict__ out) {
  int i = blockIdx.x * 256 + threadIdx.x;   // n8 unit; 2048 per matrix
  int m = i >> 11;
  int off = (i & 2047) * 8;
  const float* src;
  switch (m) {
    case 0: src = w0; break; case 1: src = w1; break; case 2: src = w2; break;
    case 3: src = w3; break; case 4: src = w4; break; default: src = w5; break;
  }
  float4 a = *(const float4*)(src + off);
  float4 b = *(const float4*)(src + off + 4);
  union { unsigned short s[8]; u32x4 u; } pk;
  pk.s[0] = f2bf(a.x); pk.s[1] = f2bf(a.y); pk.s[2] = f2bf(a.z); pk.s[3] = f2bf(a.w);
  pk.s[4] = f2bf(b.x); pk.s[5] = f2bf(b.y); pk.s[6] = f2bf(b.z); pk.s[7] = f2bf(b.w);
  *(u32x4*)(out + (size_t)m * 16384 + off) = pk.u;
}

// ---------- CSR build (XCD-partitioned by dst range) ----------
__global__ __launch_bounds__(256) void count_kernel(const int* __restrict__ dst,
                                                    int* __restrict__ cnt, int E, float pscale) {
  int p = blockIdx.x & 7;
  int blk = blockIdx.x >> 3;
  int stride = (gridDim.x >> 3) * 256;
  for (int e = blk * 256 + threadIdx.x; e < E; e += stride) {
    int d = dst[e];
    int pd = (int)((float)d * pscale);
    pd = pd > 7 ? 7 : pd;
    if (pd == p) atomicAdd(&cnt[d], 1);
  }
}

// 2048 counts per block -> blocksum[b]
__global__ __launch_bounds__(256) void partial_kernel(const int* __restrict__ cnt,
                                                      int* __restrict__ blocksum, int N) {
  __shared__ int red[256];
  int t = threadIdx.x;
  int idx = blockIdx.x * 2048 + t * 8;
  int s = 0;
  if (idx + 8 <= N) {
    int4 a = *(const int4*)(cnt + idx);
    int4 b = *(const int4*)(cnt + idx + 4);
    s = a.x + a.y + a.z + a.w + b.x + b.y + b.z + b.w;
  } else {
    for (int i = idx; i < N && i < idx + 8; ++i) s += cnt[i];
  }
  red[t] = s;
  __syncthreads();
  for (int off = 128; off > 0; off >>= 1) {
    if (t < off) red[t] += red[t + off];
    __syncthreads();
  }
  if (t == 0) blocksum[blockIdx.x] = red[0];
}

// single wave scans <=64 block partials -> exclusive blockoff[b]
__global__ __launch_bounds__(64) void scanmid_kernel(const int* __restrict__ blocksum,
                                                     int* __restrict__ blockoff, int nb) {
  int l = threadIdx.x;
  int own = (l < nb) ? blocksum[l] : 0;
  int v = own;
  for (int off = 1; off < 64; off <<= 1) {
    int u = __shfl_up(v, off);
    if (l >= off) v += u;
  }
  if (l < nb) blockoff[l] = v - own;
}

// local scan of 2048 counts + write rowstart/cursor/inv (init fused here)
__global__ __launch_bounds__(256) void final_kernel(const int* __restrict__ cnt,
                                                    const int* __restrict__ blockoff,
                                                    int* __restrict__ rowstart,
                                                    int* __restrict__ cursor,
                                                    float* __restrict__ inv, int N) {
  __shared__ int thr[256];
  int t = threadIdx.x;
  int idx = blockIdx.x * 2048 + t * 8;
  int c[8];
  int s = 0;
#pragma unroll
  for (int i = 0; i < 8; ++i) {
    int n = idx + i;
    c[i] = (n < N) ? cnt[n] : 0;
    s += c[i];
  }
  thr[t] = s;
  __syncthreads();
  for (int off = 1; off < 256; off <<= 1) {
    int u = (t >= off) ? thr[t - off] : 0;
    __syncthreads();
    thr[t] += u;
    __syncthreads();
  }
  int run = blockoff[blockIdx.x] + thr[t] - s;  // exclusive prefix for this thread
#pragma unroll
  for (int i = 0; i < 8; ++i) {
    int n = idx + i;
    if (n < N) {
      rowstart[n] = run;
      cursor[n] = run;
      inv[n] = 1.f / fmaxf((float)c[i], 1.f);
      run += c[i];
      if (n == N - 1) rowstart[N] = run;
    }
  }
}

__global__ __launch_bounds__(256) void fill_kernel(const int* __restrict__ src,
                                                   const int* __restrict__ dst,
                                                   int* __restrict__ cursor,
                                                   int* __restrict__ elist, int E, float pscale) {
  int p = blockIdx.x & 7;
  int blk = blockIdx.x >> 3;
  int stride = (gridDim.x >> 3) * 256;
  for (int e = blk * 256 + threadIdx.x; e < E; e += stride) {
    int d = dst[e];
    int s = src[e];
    int pd = (int)((float)d * pscale);
    pd = pd > 7 ? 7 : pd;
    if (pd == p) {
      int pos = atomicAdd(&cursor[d], 1);
      elist[pos] = s;
    }
  }
}

// ---------- mean aggregate: 16 lanes per node, unroll-2 gather pipeline ----------
__global__ __launch_bounds__(256) void aggregate_kernel(const unsigned short* __restrict__ xbf,
                                                        const int* __restrict__ rowstart,
                                                        const int* __restrict__ elist,
                                                        const float* __restrict__ inv,
                                                        unsigned short* __restrict__ aggbf, int N) {
  int gid = blockIdx.x * 256 + threadIdx.x;
  int node = gid >> 4;
  if (node >= N) return;
  int l16 = threadIdx.x & 15;

  int beg = rowstart[node], end = rowstart[node + 1];
  float acc[8];
#pragma unroll
  for (int j = 0; j < 8; ++j) acc[j] = 0.f;

  int e = beg;
  for (; e + 2 <= end; e += 2) {
    int s0 = elist[e];
    int s1 = elist[e + 1];
    u32x4 u0 = *(const u32x4*)(xbf + ((size_t)s0 << 7) + l16 * 8);
    u32x4 u1 = *(const u32x4*)(xbf + ((size_t)s1 << 7) + l16 * 8);
#pragma unroll
    for (int d = 0; d < 4; ++d) {
      acc[2 * d]     += __uint_as_float(u0[d] << 16);
      acc[2 * d + 1] += __uint_as_float(u0[d] & 0xffff0000u);
      acc[2 * d]     += __uint_as_float(u1[d] << 16);
      acc[2 * d + 1] += __uint_as_float(u1[d] & 0xffff0000u);
    }
  }
  if (e < end) {
    int s0 = elist[e];
    u32x4 u0 = *(const u32x4*)(xbf + ((size_t)s0 << 7) + l16 * 8);
#pragma unroll
    for (int d = 0; d < 4; ++d) {
      acc[2 * d]     += __uint_as_float(u0[d] << 16);
      acc[2 * d + 1] += __uint_as_float(u0[d] & 0xffff0000u);
    }
  }

  float iv = inv[node];
  union { unsigned short s[8]; u32x4 u; } pk;
#pragma unroll
  for (int j = 0; j < 8; ++j) pk.s[j] = f2bf(acc[j] * iv);
  *(u32x4*)(aggbf + ((size_t)node << 7) + l16 * 8) = pk.u;
}

// ---------- LDS-free fused SAGE GEMM: out = Abf@Wl^T + Xbf@Wr^T + b ----------
// block = 256 thr (4 waves), 64 rows/block, wave = 16 rows x 128 cols.
// B-fragments read directly from bf16 W in global (64KB/layer, L1/L2-hit).
// No LDS, no barrier -> occupancy limited only by VGPRs (launch_bounds 256,4).
__global__ __launch_bounds__(256, 4) void sage_gemm(
    const unsigned short* __restrict__ Abf, const unsigned short* __restrict__ Xbf,
    const unsigned short* __restrict__ Wlb, const unsigned short* __restrict__ Wrb,
    const float* __restrict__ bias,
    float* __restrict__ outf, unsigned short* __restrict__ outb, int N, int relu) {
  const int tid = threadIdx.x;
  const int l = tid & 63;
  const int w = tid >> 6;
  const int l15 = l & 15;
  const int lg = l >> 4;
  const int row0 = blockIdx.x * 64 + w * 16;
  if (row0 >= N) return;

  int r = row0 + l15;
  const int rrow = (r < N) ? r : (N - 1);

  f32x4 acc[8];
#pragma unroll
  for (int ot = 0; ot < 8; ++ot) acc[ot] = f32x4{0.f, 0.f, 0.f, 0.f};

  union frag { u32x4 u; bf16x8 v; };

#pragma unroll
  for (int h = 0; h < 2; ++h) {
    const unsigned short* Asrc = h ? Xbf : Abf;
    const unsigned short* Wsrc = h ? Wrb : Wlb;
#pragma unroll
    for (int ks = 0; ks < 4; ++ks) {
      frag af;
      af.u = *(const u32x4*)(Asrc + ((size_t)rrow << 7) + (ks * 32 + lg * 8));
      frag bq[8];
#pragma unroll
      for (int ot = 0; ot < 8; ++ot)
        bq[ot].u = *(const u32x4*)(Wsrc + (ot * 16 + l15) * 128 + (ks * 32 + lg * 8));
#pragma unroll
      for (int ot = 0; ot < 8; ++ot)
        acc[ot] = __builtin_amdgcn_mfma_f32_16x16x32_bf16(af.v, bq[ot].v, acc[ot], 0, 0, 0);
    }
  }

  float bv[8];
#pragma unroll
  for (int ot = 0; ot < 8; ++ot) bv[ot] = bias[ot * 16 + l15];

#pragma unroll
  for (int i = 0; i < 4; ++i) {
    int rr = row0 + lg * 4 + i;
    if (rr < N) {
#pragma unroll
      for (int ot = 0; ot < 8; ++ot) {
        float v = acc[ot][i] + bv[ot];
        if (relu) v = fmaxf(v, 0.f);
        size_t idx = ((size_t)rr << 7) + ot * 16 + l15;
        if (outf) outf[idx] = v;
        else outb[idx] = f2bf(v);
      }
    }
  }
}

extern "C" void kernel_launch(void* const* d_in, const int* in_sizes, int n_in,
                              void* d_out, int out_size, void* d_ws, size_t ws_size,
                              hipStream_t stream) {
  (void)n_in; (void)out_size; (void)ws_size;
  const float* x = (const float*)d_in[0];
  const int* ei = (const int*)d_in[1];     // int64 in reference -> int32 from harness
  const float* W1l = (const float*)d_in[2];
  const float* b1 = (const float*)d_in[3];
  const float* W1r = (const float*)d_in[4];
  const float* W2l = (const float*)d_in[5];
  const float* b2 = (const float*)d_in[6];
  const float* W2r = (const float*)d_in[7];
  const float* W3l = (const float*)d_in[8];
  const float* b3 = (const float*)d_in[9];
  const float* W3r = (const float*)d_in[10];
  float* out = (float*)d_out;

  const int N = in_sizes[0] / 128;
  const int E = in_sizes[1] / 2;
  const int* srcp = ei;
  const int* dstp = ei + E;
  const float pscale = 8.0f / (float)N;

  char* ws = (char*)d_ws;
  size_t off = 0;
  auto alloc = [&](size_t bytes) {
    void* p = ws + off;
    off = (off + bytes + 255) & ~(size_t)255;
    return p;
  };
  unsigned short* bufA = (unsigned short*)alloc((size_t)N * 128 * 2);
  unsigned short* bufB = (unsigned short*)alloc((size_t)N * 128 * 2);
  unsigned short* aggbf = (unsigned short*)alloc((size_t)N * 128 * 2);
  int* cnt = (int*)alloc((size_t)N * 4);
  int* rowstart = (int*)alloc((size_t)(N + 1) * 4);
  int* cursor = (int*)alloc((size_t)N * 4);
  float* inv = (float*)alloc((size_t)N * 4);
  int* elist = (int*)alloc((size_t)E * 4);
  int* blocksum = (int*)alloc(64 * 4);
  int* blockoff = (int*)alloc(64 * 4);
  unsigned short* wbf = (unsigned short*)alloc(6 * 16384 * 2);  // W1l,W1r,W2l,W2r,W3l,W3r bf16

  const int nb = (N + 2047) / 2048;  // 49 for N=100k (<=64 by construction here)

  hipMemsetAsync(cnt, 0, (size_t)N * 4, stream);
  cvt_kernel<<<(N * 128 / 8 + 255) / 256, 256, 0, stream>>>(x, bufA, N * 128 / 8);
  wcvt_kernel<<<48, 256, 0, stream>>>(W1l, W1r, W2l, W2r, W3l, W3r, wbf);
  count_kernel<<<1024, 256, 0, stream>>>(dstp, cnt, E, pscale);
  partial_kernel<<<nb, 256, 0, stream>>>(cnt, blocksum, N);
  scanmid_kernel<<<1, 64, 0, stream>>>(blocksum, blockoff, nb);
  final_kernel<<<nb, 256, 0, stream>>>(cnt, blockoff, rowstart, cursor, inv, N);
  fill_kernel<<<1024, 256, 0, stream>>>(srcp, dstp, cursor, elist, E, pscale);

  unsigned short* w1l = wbf;
  unsigned short* w1r = wbf + 16384;
  unsigned short* w2l = wbf + 2 * 16384;
  unsigned short* w2r = wbf + 3 * 16384;
  unsigned short* w3l = wbf + 4 * 16384;
  unsigned short* w3r = wbf + 5 * 16384;

  int aggBlocks = (N * 16 + 255) / 256;
  int gemmBlocks = (N + 63) / 64;

  // layer 1: bufA(x) -> bufB (relu)
  aggregate_kernel<<<aggBlocks, 256, 0, stream>>>(bufA, rowstart, elist, inv, aggbf, N);
  sage_gemm<<<gemmBlocks, 256, 0, stream>>>(aggbf, bufA, w1l, w1r, b1, nullptr, bufB, N, 1);
  // layer 2: bufB -> bufA (relu; x dead, safe to overwrite)
  aggregate_kernel<<<aggBlocks, 256, 0, stream>>>(bufB, rowstart, elist, inv, aggbf, N);
  sage_gemm<<<gemmBlocks, 256, 0, stream>>>(aggbf, bufB, w2l, w2r, b2, nullptr, bufA, N, 1);
  // layer 3: bufA -> out (no relu, fp32)
  aggregate_kernel<<<aggBlocks, 256, 0, stream>>>(bufA, rowstart, elist, inv, aggbf, N);
  sage_gemm<<<gemmBlocks, 256, 0, stream>>>(aggbf, bufA, w3l, w3r, b3, out, nullptr, N, 0);
}

// Round 12
// 387.150 us; speedup vs baseline: 1.2191x; 1.2191x over previous
//
#include <hip/hip_runtime.h>

// GraphSAGE 3-layer, N=100k E=640k D=128.
// edge_index arrives as int32 (harness converts integer inputs to int32).
// CSR build: XCD-partitioned count -> hierarchical scan -> XCD-partitioned fill.
// Per layer: mean-aggregate (16 lanes/node, unroll-2 gather pipeline),
//   fused GEMM: block = 256 rows x 64 cols (col-split 2-way), 64 rows/wave,
//   bf16 W pre-converted + staged in 32KB LDS (copy-only), mfma 16x16x32.

typedef __attribute__((ext_vector_type(8))) short bf16x8;
typedef __attribute__((ext_vector_type(4))) float f32x4;
typedef __attribute__((ext_vector_type(4))) unsigned int u32x4;

__device__ __forceinline__ unsigned short f2bf(float f) {
  unsigned u = __float_as_uint(f);
  u += 0x7fffu + ((u >> 16) & 1u);   // RNE
  return (unsigned short)(u >> 16);
}

// ---------- fp32 -> bf16 convert, 8 elems/thread ----------
__global__ __launch_bounds__(256) void cvt_kernel(const float* __restrict__ in,
                                                  unsigned short* __restrict__ out, int n8) {
  int i = blockIdx.x * 256 + threadIdx.x;
  if (i >= n8) return;
  const float4* p = (const float4*)(in + (size_t)i * 8);
  float4 a = p[0], b = p[1];
  union { unsigned short s[8]; u32x4 u; } pk;
  pk.s[0] = f2bf(a.x); pk.s[1] = f2bf(a.y); pk.s[2] = f2bf(a.z); pk.s[3] = f2bf(a.w);
  pk.s[4] = f2bf(b.x); pk.s[5] = f2bf(b.y); pk.s[6] = f2bf(b.z); pk.s[7] = f2bf(b.w);
  *(u32x4*)(out + (size_t)i * 8) = pk.u;
}

// ---------- convert 6 weight matrices (128x128 each) to bf16, one launch ----------
__global__ __launch_bounds__(256) void wcvt_kernel(const float* __restrict__ w0, const float* __restrict__ w1,
                                                   const float* __restrict__ w2, const float* __restrict__ w3,
                                                   const float* __restrict__ w4, const float* __restrict__ w5,
                                                   unsigned short* __restrict__ out) {
  int i = blockIdx.x * 256 + threadIdx.x;   // n8 unit; 2048 per matrix
  int m = i >> 11;
  int off = (i & 2047) * 8;
  const float* src;
  switch (m) {
    case 0: src = w0; break; case 1: src = w1; break; case 2: src = w2; break;
    case 3: src = w3; break; case 4: src = w4; break; default: src = w5; break;
  }
  float4 a = *(const float4*)(src + off);
  float4 b = *(const float4*)(src + off + 4);
  union { unsigned short s[8]; u32x4 u; } pk;
  pk.s[0] = f2bf(a.x); pk.s[1] = f2bf(a.y); pk.s[2] = f2bf(a.z); pk.s[3] = f2bf(a.w);
  pk.s[4] = f2bf(b.x); pk.s[5] = f2bf(b.y); pk.s[6] = f2bf(b.z); pk.s[7] = f2bf(b.w);
  *(u32x4*)(out + (size_t)m * 16384 + off) = pk.u;
}

// ---------- CSR build (XCD-partitioned by dst range) ----------
__global__ __launch_bounds__(256) void count_kernel(const int* __restrict__ dst,
                                                    int* __restrict__ cnt, int E, float pscale) {
  int p = blockIdx.x & 7;
  int blk = blockIdx.x >> 3;
  int stride = (gridDim.x >> 3) * 256;
  for (int e = blk * 256 + threadIdx.x; e < E; e += stride) {
    int d = dst[e];
    int pd = (int)((float)d * pscale);
    pd = pd > 7 ? 7 : pd;
    if (pd == p) atomicAdd(&cnt[d], 1);
  }
}

// 2048 counts per block -> blocksum[b]
__global__ __launch_bounds__(256) void partial_kernel(const int* __restrict__ cnt,
                                                      int* __restrict__ blocksum, int N) {
  __shared__ int red[256];
  int t = threadIdx.x;
  int idx = blockIdx.x * 2048 + t * 8;
  int s = 0;
  if (idx + 8 <= N) {
    int4 a = *(const int4*)(cnt + idx);
    int4 b = *(const int4*)(cnt + idx + 4);
    s = a.x + a.y + a.z + a.w + b.x + b.y + b.z + b.w;
  } else {
    for (int i = idx; i < N && i < idx + 8; ++i) s += cnt[i];
  }
  red[t] = s;
  __syncthreads();
  for (int off = 128; off > 0; off >>= 1) {
    if (t < off) red[t] += red[t + off];
    __syncthreads();
  }
  if (t == 0) blocksum[blockIdx.x] = red[0];
}

// single wave scans <=64 block partials -> exclusive blockoff[b]
__global__ __launch_bounds__(64) void scanmid_kernel(const int* __restrict__ blocksum,
                                                     int* __restrict__ blockoff, int nb) {
  int l = threadIdx.x;
  int own = (l < nb) ? blocksum[l] : 0;
  int v = own;
  for (int off = 1; off < 64; off <<= 1) {
    int u = __shfl_up(v, off);
    if (l >= off) v += u;
  }
  if (l < nb) blockoff[l] = v - own;
}

// local scan of 2048 counts + write rowstart/cursor/inv (init fused here)
__global__ __launch_bounds__(256) void final_kernel(const int* __restrict__ cnt,
                                                    const int* __restrict__ blockoff,
                                                    int* __restrict__ rowstart,
                                                    int* __restrict__ cursor,
                                                    float* __restrict__ inv, int N) {
  __shared__ int thr[256];
  int t = threadIdx.x;
  int idx = blockIdx.x * 2048 + t * 8;
  int c[8];
  int s = 0;
#pragma unroll
  for (int i = 0; i < 8; ++i) {
    int n = idx + i;
    c[i] = (n < N) ? cnt[n] : 0;
    s += c[i];
  }
  thr[t] = s;
  __syncthreads();
  for (int off = 1; off < 256; off <<= 1) {
    int u = (t >= off) ? thr[t - off] : 0;
    __syncthreads();
    thr[t] += u;
    __syncthreads();
  }
  int run = blockoff[blockIdx.x] + thr[t] - s;  // exclusive prefix for this thread
#pragma unroll
  for (int i = 0; i < 8; ++i) {
    int n = idx + i;
    if (n < N) {
      rowstart[n] = run;
      cursor[n] = run;
      inv[n] = 1.f / fmaxf((float)c[i], 1.f);
      run += c[i];
      if (n == N - 1) rowstart[N] = run;
    }
  }
}

__global__ __launch_bounds__(256) void fill_kernel(const int* __restrict__ src,
                                                   const int* __restrict__ dst,
                                                   int* __restrict__ cursor,
                                                   int* __restrict__ elist, int E, float pscale) {
  int p = blockIdx.x & 7;
  int blk = blockIdx.x >> 3;
  int stride = (gridDim.x >> 3) * 256;
  for (int e = blk * 256 + threadIdx.x; e < E; e += stride) {
    int d = dst[e];
    int s = src[e];
    int pd = (int)((float)d * pscale);
    pd = pd > 7 ? 7 : pd;
    if (pd == p) {
      int pos = atomicAdd(&cursor[d], 1);
      elist[pos] = s;
    }
  }
}

// ---------- mean aggregate: 16 lanes per node, unroll-2 gather pipeline ----------
__global__ __launch_bounds__(256) void aggregate_kernel(const unsigned short* __restrict__ xbf,
                                                        const int* __restrict__ rowstart,
                                                        const int* __restrict__ elist,
                                                        const float* __restrict__ inv,
                                                        unsigned short* __restrict__ aggbf, int N) {
  int gid = blockIdx.x * 256 + threadIdx.x;
  int node = gid >> 4;
  if (node >= N) return;
  int l16 = threadIdx.x & 15;

  int beg = rowstart[node], end = rowstart[node + 1];
  float acc[8];
#pragma unroll
  for (int j = 0; j < 8; ++j) acc[j] = 0.f;

  int e = beg;
  for (; e + 2 <= end; e += 2) {
    int s0 = elist[e];
    int s1 = elist[e + 1];
    u32x4 u0 = *(const u32x4*)(xbf + ((size_t)s0 << 7) + l16 * 8);
    u32x4 u1 = *(const u32x4*)(xbf + ((size_t)s1 << 7) + l16 * 8);
#pragma unroll
    for (int d = 0; d < 4; ++d) {
      acc[2 * d]     += __uint_as_float(u0[d] << 16);
      acc[2 * d + 1] += __uint_as_float(u0[d] & 0xffff0000u);
      acc[2 * d]     += __uint_as_float(u1[d] << 16);
      acc[2 * d + 1] += __uint_as_float(u1[d] & 0xffff0000u);
    }
  }
  if (e < end) {
    int s0 = elist[e];
    u32x4 u0 = *(const u32x4*)(xbf + ((size_t)s0 << 7) + l16 * 8);
#pragma unroll
    for (int d = 0; d < 4; ++d) {
      acc[2 * d]     += __uint_as_float(u0[d] << 16);
      acc[2 * d + 1] += __uint_as_float(u0[d] & 0xffff0000u);
    }
  }

  float iv = inv[node];
  union { unsigned short s[8]; u32x4 u; } pk;
#pragma unroll
  for (int j = 0; j < 8; ++j) pk.s[j] = f2bf(acc[j] * iv);
  *(u32x4*)(aggbf + ((size_t)node << 7) + l16 * 8) = pk.u;
}

// ---------- fused SAGE GEMM, col-split: out = Abf@Wl^T + Xbf@Wr^T + b ----------
// Grid = rowtiles x 2 col-halves. Block = 256 thr (4 waves), 256 rows x 64 cols.
// Wave = 64 rows x 64 cols: per ks-phase 4 af + 4 bq + 16 MFMA (1 bq : 4 MFMA).
// W staged bf16->LDS (32KB, pure copy), chunk-XOR swizzle kills bank conflicts.
// All waves run staging+barrier (no early return); tail guarded at C-write.
__global__ __launch_bounds__(256) void sage_gemm(
    const unsigned short* __restrict__ Abf, const unsigned short* __restrict__ Xbf,
    const unsigned short* __restrict__ Wlb, const unsigned short* __restrict__ Wrb,
    const float* __restrict__ bias,
    float* __restrict__ outf, unsigned short* __restrict__ outb, int N, int relu) {
  __shared__ __align__(16) unsigned short sW[2][64][128];  // 32 KB
  const int tid = threadIdx.x;
  const int chalf = blockIdx.x & 1;
  const int rtile = blockIdx.x >> 1;
  const int coff = chalf * 64;

  for (int it = tid; it < 2048; it += 256) {
    int m = it >> 10;
    int o = (it >> 4) & 63;
    int ch = it & 15;
    const unsigned short* wsrc = (m ? Wrb : Wlb) + (size_t)(coff + o) * 128 + ch * 8;
    *(u32x4*)&sW[m][o][(ch ^ (o & 15)) << 3] = *(const u32x4*)wsrc;
  }
  __syncthreads();

  const int l = tid & 63;
  const int w = tid >> 6;
  const int l15 = l & 15;
  const int lg = l >> 4;
  const int row_base = rtile * 256 + w * 64;

  f32x4 acc[4][4];
#pragma unroll
  for (int rt = 0; rt < 4; ++rt)
#pragma unroll
    for (int ot = 0; ot < 4; ++ot) acc[rt][ot] = f32x4{0.f, 0.f, 0.f, 0.f};

  union frag { u32x4 u; bf16x8 v; };

  int rrow[4];
#pragma unroll
  for (int rt = 0; rt < 4; ++rt) {
    int r = row_base + rt * 16 + l15;
    rrow[rt] = (r < N) ? r : (N - 1);
  }

#pragma unroll
  for (int h = 0; h < 2; ++h) {
    const unsigned short* Asrc = h ? Xbf : Abf;
#pragma unroll
    for (int ks = 0; ks < 4; ++ks) {
      frag af[4];
#pragma unroll
      for (int rt = 0; rt < 4; ++rt)
        af[rt].u = *(const u32x4*)(Asrc + ((size_t)rrow[rt] << 7) + (ks * 32 + lg * 8));
      frag bq[4];
#pragma unroll
      for (int ot = 0; ot < 4; ++ot)
        bq[ot].u = *(const u32x4*)&sW[h][ot * 16 + l15][((((ks << 2) | lg) ^ l15)) << 3];
#pragma unroll
      for (int rt = 0; rt < 4; ++rt)
#pragma unroll
        for (int ot = 0; ot < 4; ++ot)
          acc[rt][ot] = __builtin_amdgcn_mfma_f32_16x16x32_bf16(af[rt].v, bq[ot].v, acc[rt][ot], 0, 0, 0);
    }
  }

  float bv[4];
#pragma unroll
  for (int ot = 0; ot < 4; ++ot) bv[ot] = bias[coff + ot * 16 + l15];

#pragma unroll
  for (int rt = 0; rt < 4; ++rt) {
#pragma unroll
    for (int i = 0; i < 4; ++i) {
      int rr = row_base + rt * 16 + lg * 4 + i;
      if (rr < N) {
#pragma unroll
        for (int ot = 0; ot < 4; ++ot) {
          float v = acc[rt][ot][i] + bv[ot];
          if (relu) v = fmaxf(v, 0.f);
          size_t idx = ((size_t)rr << 7) + coff + ot * 16 + l15;
          if (outf) outf[idx] = v;
          else outb[idx] = f2bf(v);
        }
      }
    }
  }
}

extern "C" void kernel_launch(void* const* d_in, const int* in_sizes, int n_in,
                              void* d_out, int out_size, void* d_ws, size_t ws_size,
                              hipStream_t stream) {
  (void)n_in; (void)out_size; (void)ws_size;
  const float* x = (const float*)d_in[0];
  const int* ei = (const int*)d_in[1];     // int64 in reference -> int32 from harness
  const float* W1l = (const float*)d_in[2];
  const float* b1 = (const float*)d_in[3];
  const float* W1r = (const float*)d_in[4];
  const float* W2l = (const float*)d_in[5];
  const float* b2 = (const float*)d_in[6];
  const float* W2r = (const float*)d_in[7];
  const float* W3l = (const float*)d_in[8];
  const float* b3 = (const float*)d_in[9];
  const float* W3r = (const float*)d_in[10];
  float* out = (float*)d_out;

  const int N = in_sizes[0] / 128;
  const int E = in_sizes[1] / 2;
  const int* srcp = ei;
  const int* dstp = ei + E;
  const float pscale = 8.0f / (float)N;

  char* ws = (char*)d_ws;
  size_t off = 0;
  auto alloc = [&](size_t bytes) {
    void* p = ws + off;
    off = (off + bytes + 255) & ~(size_t)255;
    return p;
  };
  unsigned short* bufA = (unsigned short*)alloc((size_t)N * 128 * 2);
  unsigned short* bufB = (unsigned short*)alloc((size_t)N * 128 * 2);
  unsigned short* aggbf = (unsigned short*)alloc((size_t)N * 128 * 2);
  int* cnt = (int*)alloc((size_t)N * 4);
  int* rowstart = (int*)alloc((size_t)(N + 1) * 4);
  int* cursor = (int*)alloc((size_t)N * 4);
  float* inv = (float*)alloc((size_t)N * 4);
  int* elist = (int*)alloc((size_t)E * 4);
  int* blocksum = (int*)alloc(64 * 4);
  int* blockoff = (int*)alloc(64 * 4);
  unsigned short* wbf = (unsigned short*)alloc(6 * 16384 * 2);  // W1l,W1r,W2l,W2r,W3l,W3r bf16

  const int nb = (N + 2047) / 2048;  // 49 for N=100k (<=64 by construction here)

  hipMemsetAsync(cnt, 0, (size_t)N * 4, stream);
  cvt_kernel<<<(N * 128 / 8 + 255) / 256, 256, 0, stream>>>(x, bufA, N * 128 / 8);
  wcvt_kernel<<<48, 256, 0, stream>>>(W1l, W1r, W2l, W2r, W3l, W3r, wbf);
  count_kernel<<<1024, 256, 0, stream>>>(dstp, cnt, E, pscale);
  partial_kernel<<<nb, 256, 0, stream>>>(cnt, blocksum, N);
  scanmid_kernel<<<1, 64, 0, stream>>>(blocksum, blockoff, nb);
  final_kernel<<<nb, 256, 0, stream>>>(cnt, blockoff, rowstart, cursor, inv, N);
  fill_kernel<<<1024, 256, 0, stream>>>(srcp, dstp, cursor, elist, E, pscale);

  unsigned short* w1l = wbf;
  unsigned short* w1r = wbf + 16384;
  unsigned short* w2l = wbf + 2 * 16384;
  unsigned short* w2r = wbf + 3 * 16384;
  unsigned short* w3l = wbf + 4 * 16384;
  unsigned short* w3r = wbf + 5 * 16384;

  int aggBlocks = (N * 16 + 255) / 256;
  int gemmBlocks = ((N + 255) / 256) * 2;   // rowtiles x 2 col-halves

  // layer 1: bufA(x) -> bufB (relu)
  aggregate_kernel<<<aggBlocks, 256, 0, stream>>>(bufA, rowstart, elist, inv, aggbf, N);
  sage_gemm<<<gemmBlocks, 256, 0, stream>>>(aggbf, bufA, w1l, w1r, b1, nullptr, bufB, N, 1);
  // layer 2: bufB -> bufA (relu; x dead, safe to overwrite)
  aggregate_kernel<<<aggBlocks, 256, 0, stream>>>(bufB, rowstart, elist, inv, aggbf, N);
  sage_gemm<<<gemmBlocks, 256, 0, stream>>>(aggbf, bufB, w2l, w2r, b2, nullptr, bufA, N, 1);
  // layer 3: bufA -> out (no relu, fp32)
  aggregate_kernel<<<aggBlocks, 256, 0, stream>>>(bufA, rowstart, elist, inv, aggbf, N);
  sage_gemm<<<gemmBlocks, 256, 0, stream>>>(aggbf, bufA, w3l, w3r, b3, out, nullptr, N, 0);
}

// Round 14
// 384.996 us; speedup vs baseline: 1.2259x; 1.0056x over previous
//
#include <hip/hip_runtime.h>

// GraphSAGE 3-layer, N=100k E=640k D=128.
// edge_index arrives as int32 (harness converts integer inputs to int32).
// CSR build: XCD-partitioned count -> hierarchical scan -> XCD-partitioned fill.
// Per layer: mean-aggregate (16 lanes/node, unroll-4 gather pipeline),
//   fused GEMM: block = 256 rows x 64 cols (col-split 2-way), 64 rows/wave,
//   bf16 W pre-converted + staged in 32KB LDS (copy-only), mfma 16x16x32.

typedef __attribute__((ext_vector_type(8))) short bf16x8;
typedef __attribute__((ext_vector_type(4))) float f32x4;
typedef __attribute__((ext_vector_type(4))) unsigned int u32x4;

__device__ __forceinline__ unsigned short f2bf(float f) {
  unsigned u = __float_as_uint(f);
  u += 0x7fffu + ((u >> 16) & 1u);   // RNE
  return (unsigned short)(u >> 16);
}

// ---------- fp32 -> bf16 convert, 8 elems/thread ----------
__global__ __launch_bounds__(256) void cvt_kernel(const float* __restrict__ in,
                                                  unsigned short* __restrict__ out, int n8) {
  int i = blockIdx.x * 256 + threadIdx.x;
  if (i >= n8) return;
  const float4* p = (const float4*)(in + (size_t)i * 8);
  float4 a = p[0], b = p[1];
  union { unsigned short s[8]; u32x4 u; } pk;
  pk.s[0] = f2bf(a.x); pk.s[1] = f2bf(a.y); pk.s[2] = f2bf(a.z); pk.s[3] = f2bf(a.w);
  pk.s[4] = f2bf(b.x); pk.s[5] = f2bf(b.y); pk.s[6] = f2bf(b.z); pk.s[7] = f2bf(b.w);
  *(u32x4*)(out + (size_t)i * 8) = pk.u;
}

// ---------- convert 6 weight matrices (128x128 each) to bf16, one launch ----------
__global__ __launch_bounds__(256) void wcvt_kernel(const float* __restrict__ w0, const float* __restrict__ w1,
                                                   const float* __restrict__ w2, const float* __restrict__ w3,
                                                   const float* __restrict__ w4, const float* __restrict__ w5,
                                                   unsigned short* __restrict__ out) {
  int i = blockIdx.x * 256 + threadIdx.x;   // n8 unit; 2048 per matrix
  int m = i >> 11;
  int off = (i & 2047) * 8;
  const float* src;
  switch (m) {
    case 0: src = w0; break; case 1: src = w1; break; case 2: src = w2; break;
    case 3: src = w3; break; case 4: src = w4; break; default: src = w5; break;
  }
  float4 a = *(const float4*)(src + off);
  float4 b = *(const float4*)(src + off + 4);
  union { unsigned short s[8]; u32x4 u; } pk;
  pk.s[0] = f2bf(a.x); pk.s[1] = f2bf(a.y); pk.s[2] = f2bf(a.z); pk.s[3] = f2bf(a.w);
  pk.s[4] = f2bf(b.x); pk.s[5] = f2bf(b.y); pk.s[6] = f2bf(b.z); pk.s[7] = f2bf(b.w);
  *(u32x4*)(out + (size_t)m * 16384 + off) = pk.u;
}

// ---------- CSR build (XCD-partitioned by dst range) ----------
__global__ __launch_bounds__(256) void count_kernel(const int* __restrict__ dst,
                                                    int* __restrict__ cnt, int E, float pscale) {
  int p = blockIdx.x & 7;
  int blk = blockIdx.x >> 3;
  int stride = (gridDim.x >> 3) * 256;
  for (int e = blk * 256 + threadIdx.x; e < E; e += stride) {
    int d = dst[e];
    int pd = (int)((float)d * pscale);
    pd = pd > 7 ? 7 : pd;
    if (pd == p) atomicAdd(&cnt[d], 1);
  }
}

// 2048 counts per block -> blocksum[b]
__global__ __launch_bounds__(256) void partial_kernel(const int* __restrict__ cnt,
                                                      int* __restrict__ blocksum, int N) {
  __shared__ int red[256];
  int t = threadIdx.x;
  int idx = blockIdx.x * 2048 + t * 8;
  int s = 0;
  if (idx + 8 <= N) {
    int4 a = *(const int4*)(cnt + idx);
    int4 b = *(const int4*)(cnt + idx + 4);
    s = a.x + a.y + a.z + a.w + b.x + b.y + b.z + b.w;
  } else {
    for (int i = idx; i < N && i < idx + 8; ++i) s += cnt[i];
  }
  red[t] = s;
  __syncthreads();
  for (int off = 128; off > 0; off >>= 1) {
    if (t < off) red[t] += red[t + off];
    __syncthreads();
  }
  if (t == 0) blocksum[blockIdx.x] = red[0];
}

// single wave scans <=64 block partials -> exclusive blockoff[b]
__global__ __launch_bounds__(64) void scanmid_kernel(const int* __restrict__ blocksum,
                                                     int* __restrict__ blockoff, int nb) {
  int l = threadIdx.x;
  int own = (l < nb) ? blocksum[l] : 0;
  int v = own;
  for (int off = 1; off < 64; off <<= 1) {
    int u = __shfl_up(v, off);
    if (l >= off) v += u;
  }
  if (l < nb) blockoff[l] = v - own;
}

// local scan of 2048 counts + write rowstart/cursor/inv (init fused here)
__global__ __launch_bounds__(256) void final_kernel(const int* __restrict__ cnt,
                                                    const int* __restrict__ blockoff,
                                                    int* __restrict__ rowstart,
                                                    int* __restrict__ cursor,
                                                    float* __restrict__ inv, int N) {
  __shared__ int thr[256];
  int t = threadIdx.x;
  int idx = blockIdx.x * 2048 + t * 8;
  int c[8];
  int s = 0;
#pragma unroll
  for (int i = 0; i < 8; ++i) {
    int n = idx + i;
    c[i] = (n < N) ? cnt[n] : 0;
    s += c[i];
  }
  thr[t] = s;
  __syncthreads();
  for (int off = 1; off < 256; off <<= 1) {
    int u = (t >= off) ? thr[t - off] : 0;
    __syncthreads();
    thr[t] += u;
    __syncthreads();
  }
  int run = blockoff[blockIdx.x] + thr[t] - s;  // exclusive prefix for this thread
#pragma unroll
  for (int i = 0; i < 8; ++i) {
    int n = idx + i;
    if (n < N) {
      rowstart[n] = run;
      cursor[n] = run;
      inv[n] = 1.f / fmaxf((float)c[i], 1.f);
      run += c[i];
      if (n == N - 1) rowstart[N] = run;
    }
  }
}

__global__ __launch_bounds__(256) void fill_kernel(const int* __restrict__ src,
                                                   const int* __restrict__ dst,
                                                   int* __restrict__ cursor,
                                                   int* __restrict__ elist, int E, float pscale) {
  int p = blockIdx.x & 7;
  int blk = blockIdx.x >> 3;
  int stride = (gridDim.x >> 3) * 256;
  for (int e = blk * 256 + threadIdx.x; e < E; e += stride) {
    int d = dst[e];
    int s = src[e];
    int pd = (int)((float)d * pscale);
    pd = pd > 7 ? 7 : pd;
    if (pd == p) {
      int pos = atomicAdd(&cursor[d], 1);
      elist[pos] = s;
    }
  }
}

// ---------- mean aggregate: 16 lanes per node, unroll-4 gather pipeline ----------
// 4 nodes per wave -> 4 independent edge chains x 4 outstanding rows = MLP 16.
__global__ __launch_bounds__(256) void aggregate_kernel(const unsigned short* __restrict__ xbf,
                                                        const int* __restrict__ rowstart,
                                                        const int* __restrict__ elist,
                                                        const float* __restrict__ inv,
                                                        unsigned short* __restrict__ aggbf, int N) {
  int gid = blockIdx.x * 256 + threadIdx.x;
  int node = gid >> 4;
  if (node >= N) return;
  int l16 = threadIdx.x & 15;

  int beg = rowstart[node], end = rowstart[node + 1];
  float acc[8];
#pragma unroll
  for (int j = 0; j < 8; ++j) acc[j] = 0.f;

  int e = beg;
  for (; e + 4 <= end; e += 4) {
    int s0 = elist[e];
    int s1 = elist[e + 1];
    int s2 = elist[e + 2];
    int s3 = elist[e + 3];
    u32x4 u0 = *(const u32x4*)(xbf + ((size_t)s0 << 7) + l16 * 8);
    u32x4 u1 = *(const u32x4*)(xbf + ((size_t)s1 << 7) + l16 * 8);
    u32x4 u2 = *(const u32x4*)(xbf + ((size_t)s2 << 7) + l16 * 8);
    u32x4 u3 = *(const u32x4*)(xbf + ((size_t)s3 << 7) + l16 * 8);
#pragma unroll
    for (int d = 0; d < 4; ++d) {
      acc[2 * d]     += __uint_as_float(u0[d] << 16);
      acc[2 * d + 1] += __uint_as_float(u0[d] & 0xffff0000u);
      acc[2 * d]     += __uint_as_float(u1[d] << 16);
      acc[2 * d + 1] += __uint_as_float(u1[d] & 0xffff0000u);
      acc[2 * d]     += __uint_as_float(u2[d] << 16);
      acc[2 * d + 1] += __uint_as_float(u2[d] & 0xffff0000u);
      acc[2 * d]     += __uint_as_float(u3[d] << 16);
      acc[2 * d + 1] += __uint_as_float(u3[d] & 0xffff0000u);
    }
  }
  for (; e < end; ++e) {
    int s0 = elist[e];
    u32x4 u0 = *(const u32x4*)(xbf + ((size_t)s0 << 7) + l16 * 8);
#pragma unroll
    for (int d = 0; d < 4; ++d) {
      acc[2 * d]     += __uint_as_float(u0[d] << 16);
      acc[2 * d + 1] += __uint_as_float(u0[d] & 0xffff0000u);
    }
  }

  float iv = inv[node];
  union { unsigned short s[8]; u32x4 u; } pk;
#pragma unroll
  for (int j = 0; j < 8; ++j) pk.s[j] = f2bf(acc[j] * iv);
  *(u32x4*)(aggbf + ((size_t)node << 7) + l16 * 8) = pk.u;
}

// ---------- fused SAGE GEMM, col-split: out = Abf@Wl^T + Xbf@Wr^T + b ----------
// Grid = rowtiles x 2 col-halves. Block = 256 thr (4 waves), 256 rows x 64 cols.
// Wave = 64 rows x 64 cols: per ks-phase 4 af + 4 bq + 16 MFMA (1 bq : 4 MFMA).
// W staged bf16->LDS (32KB, pure copy), chunk-XOR swizzle kills bank conflicts.
__global__ __launch_bounds__(256) void sage_gemm(
    const unsigned short* __restrict__ Abf, const unsigned short* __restrict__ Xbf,
    const unsigned short* __restrict__ Wlb, const unsigned short* __restrict__ Wrb,
    const float* __restrict__ bias,
    float* __restrict__ outf, unsigned short* __restrict__ outb, int N, int relu) {
  __shared__ __align__(16) unsigned short sW[2][64][128];  // 32 KB
  const int tid = threadIdx.x;
  const int chalf = blockIdx.x & 1;
  const int rtile = blockIdx.x >> 1;
  const int coff = chalf * 64;

  for (int it = tid; it < 2048; it += 256) {
    int m = it >> 10;
    int o = (it >> 4) & 63;
    int ch = it & 15;
    const unsigned short* wsrc = (m ? Wrb : Wlb) + (size_t)(coff + o) * 128 + ch * 8;
    *(u32x4*)&sW[m][o][(ch ^ (o & 15)) << 3] = *(const u32x4*)wsrc;
  }
  __syncthreads();

  const int l = tid & 63;
  const int w = tid >> 6;
  const int l15 = l & 15;
  const int lg = l >> 4;
  const int row_base = rtile * 256 + w * 64;

  f32x4 acc[4][4];
#pragma unroll
  for (int rt = 0; rt < 4; ++rt)
#pragma unroll
    for (int ot = 0; ot < 4; ++ot) acc[rt][ot] = f32x4{0.f, 0.f, 0.f, 0.f};

  union frag { u32x4 u; bf16x8 v; };

  int rrow[4];
#pragma unroll
  for (int rt = 0; rt < 4; ++rt) {
    int r = row_base + rt * 16 + l15;
    rrow[rt] = (r < N) ? r : (N - 1);
  }

#pragma unroll
  for (int h = 0; h < 2; ++h) {
    const unsigned short* Asrc = h ? Xbf : Abf;
#pragma unroll
    for (int ks = 0; ks < 4; ++ks) {
      frag af[4];
#pragma unroll
      for (int rt = 0; rt < 4; ++rt)
        af[rt].u = *(const u32x4*)(Asrc + ((size_t)rrow[rt] << 7) + (ks * 32 + lg * 8));
      frag bq[4];
#pragma unroll
      for (int ot = 0; ot < 4; ++ot)
        bq[ot].u = *(const u32x4*)&sW[h][ot * 16 + l15][((((ks << 2) | lg) ^ l15)) << 3];
#pragma unroll
      for (int rt = 0; rt < 4; ++rt)
#pragma unroll
        for (int ot = 0; ot < 4; ++ot)
          acc[rt][ot] = __builtin_amdgcn_mfma_f32_16x16x32_bf16(af[rt].v, bq[ot].v, acc[rt][ot], 0, 0, 0);
    }
  }

  float bv[4];
#pragma unroll
  for (int ot = 0; ot < 4; ++ot) bv[ot] = bias[coff + ot * 16 + l15];

#pragma unroll
  for (int rt = 0; rt < 4; ++rt) {
#pragma unroll
    for (int i = 0; i < 4; ++i) {
      int rr = row_base + rt * 16 + lg * 4 + i;
      if (rr < N) {
#pragma unroll
        for (int ot = 0; ot < 4; ++ot) {
          float v = acc[rt][ot][i] + bv[ot];
          if (relu) v = fmaxf(v, 0.f);
          size_t idx = ((size_t)rr << 7) + coff + ot * 16 + l15;
          if (outf) outf[idx] = v;
          else outb[idx] = f2bf(v);
        }
      }
    }
  }
}

extern "C" void kernel_launch(void* const* d_in, const int* in_sizes, int n_in,
                              void* d_out, int out_size, void* d_ws, size_t ws_size,
                              hipStream_t stream) {
  (void)n_in; (void)out_size; (void)ws_size;
  const float* x = (const float*)d_in[0];
  const int* ei = (const int*)d_in[1];     // int64 in reference -> int32 from harness
  const float* W1l = (const float*)d_in[2];
  const float* b1 = (const float*)d_in[3];
  const float* W1r = (const float*)d_in[4];
  const float* W2l = (const float*)d_in[5];
  const float* b2 = (const float*)d_in[6];
  const float* W2r = (const float*)d_in[7];
  const float* W3l = (const float*)d_in[8];
  const float* b3 = (const float*)d_in[9];
  const float* W3r = (const float*)d_in[10];
  float* out = (float*)d_out;

  const int N = in_sizes[0] / 128;
  const int E = in_sizes[1] / 2;
  const int* srcp = ei;
  const int* dstp = ei + E;
  const float pscale = 8.0f / (float)N;

  char* ws = (char*)d_ws;
  size_t off = 0;
  auto alloc = [&](size_t bytes) {
    void* p = ws + off;
    off = (off + bytes + 255) & ~(size_t)255;
    return p;
  };
  unsigned short* bufA = (unsigned short*)alloc((size_t)N * 128 * 2);
  unsigned short* bufB = (unsigned short*)alloc((size_t)N * 128 * 2);
  unsigned short* aggbf = (unsigned short*)alloc((size_t)N * 128 * 2);
  int* cnt = (int*)alloc((size_t)N * 4);
  int* rowstart = (int*)alloc((size_t)(N + 1) * 4);
  int* cursor = (int*)alloc((size_t)N * 4);
  float* inv = (float*)alloc((size_t)N * 4);
  int* elist = (int*)alloc((size_t)E * 4);
  int* blocksum = (int*)alloc(64 * 4);
  int* blockoff = (int*)alloc(64 * 4);
  unsigned short* wbf = (unsigned short*)alloc(6 * 16384 * 2);  // W1l,W1r,W2l,W2r,W3l,W3r bf16

  const int nb = (N + 2047) / 2048;  // 49 for N=100k (<=64 by construction here)

  hipMemsetAsync(cnt, 0, (size_t)N * 4, stream);
  cvt_kernel<<<(N * 128 / 8 + 255) / 256, 256, 0, stream>>>(x, bufA, N * 128 / 8);
  wcvt_kernel<<<48, 256, 0, stream>>>(W1l, W1r, W2l, W2r, W3l, W3r, wbf);
  count_kernel<<<1024, 256, 0, stream>>>(dstp, cnt, E, pscale);
  partial_kernel<<<nb, 256, 0, stream>>>(cnt, blocksum, N);
  scanmid_kernel<<<1, 64, 0, stream>>>(blocksum, blockoff, nb);
  final_kernel<<<nb, 256, 0, stream>>>(cnt, blockoff, rowstart, cursor, inv, N);
  fill_kernel<<<1024, 256, 0, stream>>>(srcp, dstp, cursor, elist, E, pscale);

  unsigned short* w1l = wbf;
  unsigned short* w1r = wbf + 16384;
  unsigned short* w2l = wbf + 2 * 16384;
  unsigned short* w2r = wbf + 3 * 16384;
  unsigned short* w3l = wbf + 4 * 16384;
  unsigned short* w3r = wbf + 5 * 16384;

  int aggBlocks = (N * 16 + 255) / 256;
  int gemmBlocks = ((N + 255) / 256) * 2;   // rowtiles x 2 col-halves

  // layer 1: bufA(x) -> bufB (relu)
  aggregate_kernel<<<aggBlocks, 256, 0, stream>>>(bufA, rowstart, elist, inv, aggbf, N);
  sage_gemm<<<gemmBlocks, 256, 0, stream>>>(aggbf, bufA, w1l, w1r, b1, nullptr, bufB, N, 1);
  // layer 2: bufB -> bufA (relu; x dead, safe to overwrite)
  aggregate_kernel<<<aggBlocks, 256, 0, stream>>>(bufB, rowstart, elist, inv, aggbf, N);
  sage_gemm<<<gemmBlocks, 256, 0, stream>>>(aggbf, bufB, w2l, w2r, b2, nullptr, bufA, N, 1);
  // layer 3: bufA -> out (no relu, fp32)
  aggregate_kernel<<<aggBlocks, 256, 0, stream>>>(bufA, rowstart, elist, inv, aggbf, N);
  sage_gemm<<<gemmBlocks, 256, 0, stream>>>(aggbf, bufA, w3l, w3r, b3, out, nullptr, N, 0);
}